// Round 9
// baseline (198.341 us; speedup 1.0000x reference)
//
#include <hip/hip_runtime.h>
#include <hip/hip_bf16.h>
#include <stdint.h>

#define T_ 2
#define N_ 4096
#define D_ 1024
#define E_ 8
#define O_ 1024

#define BM 128
#define BN 128
#define BK 32

typedef __attribute__((ext_vector_type(8))) short short8;
typedef __attribute__((ext_vector_type(4))) float f32x4;

#define AS1 __attribute__((address_space(1)))
#define AS3 __attribute__((address_space(3)))

// async global->LDS, 16B per lane; LDS dest = base + lane*16 (wave-uniform base)
__device__ inline void gld16(const unsigned short* g, unsigned short* l) {
    __builtin_amdgcn_global_load_lds((const AS1 unsigned int*)g,
                                     (AS3 unsigned int*)l, 16, 0, 0);
}

__device__ inline unsigned short f2bf(float f) {
    union { float f; unsigned u; } v; v.f = f;
    unsigned r = v.u + 0x7fff + ((v.u >> 16) & 1);  // RNE
    return (unsigned short)(r >> 16);
}

// ---------------------------------------------------------------------------
// Kernel 1 (fused, 3 ranges):
//   blocks    0..1023: gating + x->bf16 (8 tokens/block)
//   blocks 1024..2047: We fp32 [e][d][o] -> bf16 MFMA-fragment order Wf
//   blocks 2048..4095: zero-fill out (32MB) for the GEMM's fp32 atomics
// All three touch disjoint data; fusing overlaps their HBM traffic.
//   Wf chunk index = (((e8*32 + ks)*8 + cb)*64 + lane), 8 bf16 per chunk,
//   e8 = e*8+ot, ks = k-step, cb = 16-col block, lane = fr + 16q;
//   value j = We[e][d = ks*32 + q*8 + j][o = ot*128 + cb*16 + fr].
// ---------------------------------------------------------------------------
__global__ __launch_bounds__(256) void prep_kernel(
    const float* __restrict__ x, const float* __restrict__ Wg,
    const float* __restrict__ We,
    unsigned short* __restrict__ xb, unsigned short* __restrict__ Wbp,
    int* __restrict__ route, float2* __restrict__ gpair,
    float* __restrict__ out)
{
    __shared__ __align__(16) char smem[E_ * D_ * 4];   // 32 KB (gate); pack uses 17.4 KB
    int tid = threadIdx.x;

    if (blockIdx.x >= 2048) {
        // ---- zero half: 2048 blocks x 16KB = 32MB ----
        float4 z = {0.f, 0.f, 0.f, 0.f};
        float4* dst = (float4*)out + (size_t)(blockIdx.x - 2048) * 1024;
#pragma unroll
        for (int k = 0; k < 4; ++k) dst[k * 256 + tid] = z;
        return;
    }

    if (blockIdx.x < 1024) {
        // ---- gate half ----
        float (*WgT)[D_] = (float(*)[D_])smem;
        int wave = tid >> 6, lane = tid & 63;
        int token0 = blockIdx.x * 8;
        int t = token0 >> 12;                 // 8 consecutive tokens share t
        const float* wgb = Wg + (size_t)t * D_ * E_;

#pragma unroll
        for (int r = 0; r < 8; ++r) {
            int f = r * 1024 + tid * 4;       // flat Wg index; (d=f>>3, e=f&7)
            float4 v = *(const float4*)(wgb + f);
            WgT[f & 7][f >> 3]             = v.x;
            WgT[(f + 1) & 7][(f + 1) >> 3] = v.y;
            WgT[(f + 2) & 7][(f + 2) >> 3] = v.z;
            WgT[(f + 3) & 7][(f + 3) >> 3] = v.w;
        }
        __syncthreads();

#pragma unroll
        for (int tl = 0; tl < 2; ++tl) {
            int token = token0 + wave * 2 + tl;
            const float* xrow = x + (size_t)token * D_;

            float4 xv[4];
#pragma unroll
            for (int c = 0; c < 4; ++c)
                xv[c] = *(const float4*)(xrow + c * 256 + lane * 4);

            float acc[E_] = {0.f, 0.f, 0.f, 0.f, 0.f, 0.f, 0.f, 0.f};
#pragma unroll
            for (int c = 0; c < 4; ++c) {
                int d0 = c * 256 + lane * 4;
                unsigned lo = f2bf(xv[c].x) | ((unsigned)f2bf(xv[c].y) << 16);
                unsigned hi = f2bf(xv[c].z) | ((unsigned)f2bf(xv[c].w) << 16);
                *(uint2*)(&xb[(size_t)token * D_ + d0]) = make_uint2(lo, hi);
#pragma unroll
                for (int e = 0; e < E_; ++e) {
                    float4 w = *(const float4*)(&WgT[e][d0]);
                    acc[e] += xv[c].x * w.x + xv[c].y * w.y + xv[c].z * w.z + xv[c].w * w.w;
                }
            }
#pragma unroll
            for (int off = 1; off < 64; off <<= 1) {
#pragma unroll
                for (int e = 0; e < E_; ++e) acc[e] += __shfl_xor(acc[e], off, 64);
            }

            if (lane == 0) {
                // top-2, lowest-index-first on ties (matches jax.lax.top_k)
                float best = acc[0]; int bi = 0;
#pragma unroll
                for (int e = 1; e < E_; ++e) if (acc[e] > best) { best = acc[e]; bi = e; }
                float sec = -INFINITY; int si = 0;
#pragma unroll
                for (int e = 0; e < E_; ++e) if (e != bi && acc[e] > sec) { sec = acc[e]; si = e; }
                float s = best + sec + 1e-9f;
                route[token] = bi | (si << 8);
                gpair[token] = make_float2(best / s, sec / s);
            }
        }
    } else {
        // ---- pack half: fragment-order Wf ----
        unsigned short* P = (unsigned short*)smem;   // [64][136] = 17.4 KB

        int b = blockIdx.x - 1024;
        int e  = b >> 7;
        int oy = (b & 127) >> 3;   // 0..15  (o-block of 64)
        int dz = b & 7;            // 0..7   (d-block of 128)
        int o0 = oy * 64, d0 = dz * 128;

        // stage P[o_local 0..63][d_local 0..127], stride 136 (16B-aligned rows)
#pragma unroll
        for (int r = 0; r < 32; ++r) {
            int lin = r * 256 + tid;
            int dd = lin >> 6, oo = lin & 63;
            P[oo * 136 + dd] = f2bf(We[((size_t)(e * D_ + d0 + dd)) * O_ + o0 + oo]);
        }
        __syncthreads();

        // emit 1024 fragment chunks of 16B: ci -> (ks' 0..3, c16' 0..3, lane 0..63)
#pragma unroll
        for (int w = 0; w < 4; ++w) {
            int ci   = w * 256 + tid;
            int lane = ci & 63;
            int c16  = (ci >> 6) & 3;
            int ks   = ci >> 8;
            int fr = lane & 15, q = lane >> 4;
            uint4 v = *(const uint4*)&P[(c16 * 16 + fr) * 136 + ks * 32 + q * 8];
            int ot  = oy >> 1;
            int cb  = (oy * 4 + c16) & 7;
            int ksa = dz * 4 + ks;
            size_t idx = ((((size_t)(e * 8 + ot) * 32 + ksa) * 8 + cb) * 64 + lane) * 8;
            *(uint4*)(Wbp + idx) = v;
        }
    }
}

// ---------------------------------------------------------------------------
// Kernel 1b: deterministic stream compaction, SINGLE-PASS (r17).
// Was 4 serial rounds x {load + 2 barriers}; now each thread owns 4
// consecutive tokens (int4 route load), wave shfl-scan + one barrier.
// toklist entry = n | (slot<<16); slot = 0 if e is token's primary expert.
// ---------------------------------------------------------------------------
__global__ __launch_bounds__(1024) void build_lists(
    const int* __restrict__ route, const float2* __restrict__ gpair,
    int* __restrict__ toklist, float* __restrict__ gatelist,
    int* __restrict__ counts)
{
    int g = blockIdx.x;              // t*8 + e
    int t = g >> 3, e = g & 7;
    int tid = threadIdx.x;
    int wave = tid >> 6, lane = tid & 63;

    __shared__ int waveSum[16];

    int4 r4 = *(const int4*)(route + t * N_ + tid * 4);
    int rr[4] = {r4.x, r4.y, r4.z, r4.w};
    int sel[4], slot[4], mycnt = 0;
#pragma unroll
    for (int j = 0; j < 4; ++j) {
        int e0 = rr[j] & 255, e1 = (rr[j] >> 8) & 255;
        sel[j]  = (e0 == e) || (e1 == e);
        slot[j] = (e0 == e) ? 0 : 1;
        mycnt  += sel[j];
    }
    // inclusive wave scan of mycnt
    int x = mycnt;
#pragma unroll
    for (int off = 1; off < 64; off <<= 1) {
        int y = __shfl_up(x, off, 64);
        if (lane >= off) x += y;
    }
    if (lane == 63) waveSum[wave] = x;
    __syncthreads();
    int woff = 0, total = 0;
#pragma unroll
    for (int w = 0; w < 16; ++w) {
        int s = waveSum[w];
        total += s;
        woff += (w < wave) ? s : 0;
    }
    int p = woff + x - mycnt;        // exclusive prefix
#pragma unroll
    for (int j = 0; j < 4; ++j) {
        if (sel[j]) {
            int n = tid * 4 + j;
            toklist[g * N_ + p] = n | (slot[j] << 16);
            float2 gp = gpair[t * N_ + n];
            gatelist[g * N_ + p] = (slot[j] == 0) ? gp.x : gp.y;
            ++p;
        }
    }
    if (tid == 0) counts[g] = total;
}

// ---------------------------------------------------------------------------
// Kernel 3: grouped GEMM, round 17 = r15 exact (best: 63us) with an
// fp32-ATOMIC epilogue (unsafeAtomicAdd -> global_atomic_add_f32, executed
// at L2).  Each out element gets exactly 2 adds (primary+secondary expert)
// -- commutative, deterministic, and MORE accurate than the old
// bf16-slot-pack (no truncation).  combine_kernel deleted; out zeroed by
// prep's third block range.
// r16 post-mortem: 8-barrier rounds = null (62.6), FETCH +25MB -> reverted.
// The 128^2 family is schedule-invariant at ~63us / 546 TF; this round
// attacks the ~114us non-GEMM side instead.
// ---------------------------------------------------------------------------
__global__ __launch_bounds__(512, 4) void moe_gemm(
    const unsigned short* __restrict__ xb,   // [T*N][D] bf16
    const unsigned short* __restrict__ Wbp,  // fragment-order Wf (see prep)
    const int* __restrict__ toklist, const float* __restrict__ gatelist,
    const int* __restrict__ counts, float* __restrict__ out)
{
    int lin = blockIdx.x;            // 0..4095
    int mt  = lin >> 7;              // slowest: real tiles (mt < ~9) first
    int u   = lin & 127;
    int xcd = u & 7;                 // == lin % 8 == hw XCD round-robin
    int v   = u >> 3;                // 0..15
    int g   = 2 * xcd + (v >> 3);    // xcd owns groups {2x, 2x+1}
    int ot  = v & 7;
    int t   = g >> 3;

    int cnt = counts[g];
    int m0 = mt * BM;
    if (m0 >= cnt) return;

    __shared__ __align__(16) unsigned short As[2][BM * BK];  // 16 KB
    __shared__ int   tokS[BM];
    __shared__ float gateS[BM];

    int tid = threadIdx.x;
    if (tid < BM) {
        int r = m0 + tid;
        tokS[tid]  = (r < cnt) ? toklist[g * N_ + r]  : -1;
        gateS[tid] = (r < cnt) ? gatelist[g * N_ + r] : 0.f;
    }
    __syncthreads();   // queues drained entering the pipeline

    int wave = tid >> 6, lane = tid & 63;   // 8 waves
    // A staging: wave w stages 16-row chunk w (rows 16w..16w+15), 1 KB.
    // lane l -> row (l>>2) of chunk, LDS granule (l&3); source granule
    // sg = (l&3)^((l>>3)&3): LDS pos p of row r holds granule p^((r>>1)&3).
    int lr = lane >> 2;
    int sg = (lane & 3) ^ ((lane >> 3) & 3);
    int ar = wave * 16 + lr;
    int tok = max(tokS[ar], 0) & 0xFFFF;     // junk rows masked in epilogue
    const unsigned short* ag = xb + ((size_t)(t * N_ + tok)) * D_ + sg * 8;

    // B fragment pointers: e8 = (g&7)*8+ot; per-ks stride 4096 shorts;
    // per-cb stride 512; lane offset lane*8.
    const unsigned short* wf =
        Wbp + ((size_t)((g & 7) * 8 + ot) * 32) * 4096;
    int cb0 = (wave >> 1) * 2;
    const unsigned short* bp0 = wf + cb0 * 512 + lane * 8;
    const unsigned short* bp1 = bp0 + 512;

    int fr = lane & 15, q = lane >> 4;
    int wm = (wave & 1) * 64;                // 2 x 4 wave grid: 64 x 32 / wave
    int wn = (wave >> 1) * 32;
    int fp = (q ^ ((fr >> 1) & 3)) * 8;      // read-side swizzled granule

    f32x4 acc[4][2];
#pragma unroll
    for (int mi = 0; mi < 4; ++mi)
#pragma unroll
        for (int ni = 0; ni < 2; ++ni) acc[mi][ni] = (f32x4){0.f, 0.f, 0.f, 0.f};

    short8 bf0[2], bf1[2];

    // prologue: A(0) then (fence) B(0) -- order pins A oldest in the queue
    gld16(ag, &As[0][wave * 512]);
    asm volatile("" ::: "memory");
    bf0[0] = *(const short8*)(bp0);
    bf0[1] = *(const short8*)(bp1);

#define KSTEP(CUR, NXT, BC, BNX, IT)                                           \
    {                                                                          \
        asm volatile("s_waitcnt vmcnt(2)" ::: "memory"); /* A(IT) landed */    \
        __builtin_amdgcn_s_barrier();                                          \
        asm volatile("" ::: "memory");   /* no LDS ops cross the barrier */    \
        int kk = (IT) + 1;                                                     \
        if (kk < D_ / BK) {                                                    \
            gld16(ag + (size_t)kk * BK, &As[NXT][wave * 512]);                 \
            asm volatile("" ::: "memory");  /* pin A-before-B issue order */   \
            BNX[0] = *(const short8*)(bp0 + (size_t)kk * 4096);                \
            BNX[1] = *(const short8*)(bp1 + (size_t)kk * 4096);                \
        }                                                                      \
        short8 af[4];                                                          \
        _Pragma("unroll") for (int mi = 0; mi < 4; ++mi)                       \
            af[mi] = *(const short8*)(&As[CUR][(wm + mi * 16 + fr) * BK + fp]);\
        _Pragma("unroll") for (int mi = 0; mi < 4; ++mi) {                     \
            acc[mi][0] = __builtin_amdgcn_mfma_f32_16x16x32_bf16(              \
                af[mi], BC[0], acc[mi][0], 0, 0, 0);                           \
            acc[mi][1] = __builtin_amdgcn_mfma_f32_16x16x32_bf16(              \
                af[mi], BC[1], acc[mi][1], 0, 0, 0);                           \
        }                                                                      \
    }

    for (int it = 0; it < D_ / BK; it += 2) {
        KSTEP(0, 1, bf0, bf1, it)
        KSTEP(1, 0, bf1, bf0, it + 1)
    }
#undef KSTEP

    // epilogue: C/D layout col = lane&15, row = q*4 + reg  [m89/m91]
    // fp32 atomic add; out pre-zeroed by prep.  2 adds/element total.
    float* outb = out + (size_t)t * N_ * O_;
    int ncol = ot * 128 + wn + fr;
#pragma unroll
    for (int mi = 0; mi < 4; ++mi) {
#pragma unroll
        for (int r = 0; r < 4; ++r) {
            int ml = wm + mi * 16 + q * 4 + r;
            int ent = tokS[ml];
            if (ent >= 0) {
                int tokk = ent & 0xFFFF;
                float gate = gateS[ml];
                float* orow = outb + (size_t)tokk * O_ + ncol;
#pragma unroll
                for (int ni = 0; ni < 2; ++ni)
                    unsafeAtomicAdd(orow + ni * 16, gate * acc[mi][ni][r]);
            }
        }
    }
}

// ---------------------------------------------------------------------------
extern "C" void kernel_launch(void* const* d_in, const int* in_sizes, int n_in,
                              void* d_out, int out_size, void* d_ws, size_t ws_size,
                              hipStream_t stream)
{
    const float* x  = (const float*)d_in[0];
    const float* Wg = (const float*)d_in[1];
    const float* We = (const float*)d_in[2];
    float* out = (float*)d_out;

    char* ws = (char*)d_ws;
    unsigned short* xb   = (unsigned short*)(ws);               // 16,777,216 B
    unsigned short* Wbp  = (unsigned short*)(ws + 16777216);    // 16,777,216 B
    int*   toklist       = (int*)  (ws + 33554432);             //    262,144 B
    float* gatelist      = (float*)(ws + 33816576);             //    262,144 B
    int*   counts        = (int*)  (ws + 34078720);             //        256 B
    int*   route         = (int*)  (ws + 34078976);             //     32,768 B
    float2* gpair        = (float2*)(ws + 34111744);            //     65,536 B

    prep_kernel<<<4096, 256, 0, stream>>>(x, Wg, We, xb, Wbp, route, gpair, out);
    build_lists<<<T_ * E_, 1024, 0, stream>>>(route, gpair, toklist, gatelist, counts);
    moe_gemm<<<(N_ / BM) * 8 * (T_ * E_), 512, 0, stream>>>(
        xb, Wbp, toklist, gatelist, counts, out);
}

// Round 11
// 179.042 us; speedup vs baseline: 1.1078x; 1.1078x over previous
//
#include <hip/hip_runtime.h>
#include <hip/hip_bf16.h>
#include <stdint.h>

#define T_ 2
#define N_ 4096
#define D_ 1024
#define E_ 8
#define O_ 1024

#define BM 128
#define BN 128
#define BK 32

typedef __attribute__((ext_vector_type(8))) short short8;
typedef __attribute__((ext_vector_type(4))) float f32x4;

#define AS1 __attribute__((address_space(1)))
#define AS3 __attribute__((address_space(3)))

// async global->LDS, 16B per lane; LDS dest = base + lane*16 (wave-uniform base)
__device__ inline void gld16(const unsigned short* g, unsigned short* l) {
    __builtin_amdgcn_global_load_lds((const AS1 unsigned int*)g,
                                     (AS3 unsigned int*)l, 16, 0, 0);
}

__device__ inline unsigned short f2bf(float f) {
    union { float f; unsigned u; } v; v.f = f;
    unsigned r = v.u + 0x7fff + ((v.u >> 16) & 1);  // RNE
    return (unsigned short)(r >> 16);
}

// ---------------------------------------------------------------------------
// Kernel 1 (fused): blocks 0..511 = gating + x->bf16, 16 TOKENS/block
// (Wg re-stage traffic + LDS scatter halved vs 8-token blocks);
// blocks 512..1535 = pack We -> fragment-order Wf, FLOAT4-COALESCED.
// r18 BUGFIX: pack LDS row stride 33 -> 40 shorts (80 B).  33-short rows
// put odd-row ds_read_b128 at 2B alignment -> UB/fault (likely the r18
// container crash).  80 B rows are 16B-aligned; emit-read bank check:
// bank start (row*20)%32, 2 lanes/bank per quarter-phase = b128 minimum.
// Fragment layout (unchanged):
//   Wf chunk = (((e8*32 + ks)*8 + cb)*64 + lane)*8 shorts, e8 = e*8+ot,
//   lane = fr+16q; value j = We[e][ks*32 + q*8 + j][ot*128 + cb*16 + fr].
// ---------------------------------------------------------------------------
__global__ __launch_bounds__(256) void prep_kernel(
    const float* __restrict__ x, const float* __restrict__ Wg,
    const float* __restrict__ We,
    unsigned short* __restrict__ xb, unsigned short* __restrict__ Wbp,
    int* __restrict__ route, float2* __restrict__ gpair)
{
    __shared__ __align__(16) char smem[E_ * D_ * 4];   // 32 KB gate / 20.5 KB pack
    int tid = threadIdx.x;

    if (blockIdx.x < 512) {
        // ---- gate half: 16 tokens/block ----
        float (*WgT)[D_] = (float(*)[D_])smem;
        int wave = tid >> 6, lane = tid & 63;
        int token0 = blockIdx.x * 16;
        int t = token0 >> 12;                 // 16 consecutive tokens share t
        const float* wgb = Wg + (size_t)t * D_ * E_;

#pragma unroll
        for (int r = 0; r < 8; ++r) {
            int f = r * 1024 + tid * 4;       // flat Wg index; (d=f>>3, e=f&7)
            float4 v = *(const float4*)(wgb + f);
            WgT[f & 7][f >> 3]             = v.x;
            WgT[(f + 1) & 7][(f + 1) >> 3] = v.y;
            WgT[(f + 2) & 7][(f + 2) >> 3] = v.z;
            WgT[(f + 3) & 7][(f + 3) >> 3] = v.w;
        }
        __syncthreads();

#pragma unroll
        for (int tl = 0; tl < 4; ++tl) {
            int token = token0 + wave * 4 + tl;
            const float* xrow = x + (size_t)token * D_;

            float4 xv[4];
#pragma unroll
            for (int c = 0; c < 4; ++c)
                xv[c] = *(const float4*)(xrow + c * 256 + lane * 4);

            float acc[E_] = {0.f, 0.f, 0.f, 0.f, 0.f, 0.f, 0.f, 0.f};
#pragma unroll
            for (int c = 0; c < 4; ++c) {
                int d0 = c * 256 + lane * 4;
                unsigned lo = f2bf(xv[c].x) | ((unsigned)f2bf(xv[c].y) << 16);
                unsigned hi = f2bf(xv[c].z) | ((unsigned)f2bf(xv[c].w) << 16);
                *(uint2*)(&xb[(size_t)token * D_ + d0]) = make_uint2(lo, hi);
#pragma unroll
                for (int e = 0; e < E_; ++e) {
                    float4 w = *(const float4*)(&WgT[e][d0]);
                    acc[e] += xv[c].x * w.x + xv[c].y * w.y + xv[c].z * w.z + xv[c].w * w.w;
                }
            }
#pragma unroll
            for (int off = 1; off < 64; off <<= 1) {
#pragma unroll
                for (int e = 0; e < E_; ++e) acc[e] += __shfl_xor(acc[e], off, 64);
            }

            if (lane == 0) {
                // top-2, lowest-index-first on ties (matches jax.lax.top_k)
                float best = acc[0]; int bi = 0;
#pragma unroll
                for (int e = 1; e < E_; ++e) if (acc[e] > best) { best = acc[e]; bi = e; }
                float sec = -INFINITY; int si = 0;
#pragma unroll
                for (int e = 0; e < E_; ++e) if (e != bi && acc[e] > sec) { sec = acc[e]; si = e; }
                float s = best + sec + 1e-9f;
                route[token] = bi | (si << 8);
                gpair[token] = make_float2(best / s, sec / s);
            }
        }
    } else {
        // ---- pack half: (e, dz 0..31, ob 0..3) -> 32 d x 256 o slab ----
        unsigned short* P = (unsigned short*)smem;   // [256][40] bf16, 20.5 KB

        int b  = blockIdx.x - 512;
        int e  = b >> 7;
        int r7 = b & 127;
        int dz = r7 >> 2;          // k-step 0..31, d0 = dz*32
        int ob = r7 & 3;           // o-slab 0..3, o0 = ob*256
        int d0 = dz * 32, o0 = ob * 256;

        // stage: 8 iters x 256 thr: float4 along o (1KB per wave-instr)
#pragma unroll
        for (int it = 0; it < 8; ++it) {
            int lin = it * 256 + tid;
            int dd = lin >> 6, o4 = lin & 63;
            float4 v = *(const float4*)(We + ((size_t)(e * D_ + d0 + dd)) * O_ + o0 + o4 * 4);
            P[(o4 * 4 + 0) * 40 + dd] = f2bf(v.x);
            P[(o4 * 4 + 1) * 40 + dd] = f2bf(v.y);
            P[(o4 * 4 + 2) * 40 + dd] = f2bf(v.z);
            P[(o4 * 4 + 3) * 40 + dd] = f2bf(v.w);
        }
        __syncthreads();

        // emit: 4 iters x 256 thr: 16B fragment chunks, 1KB/wave-instr stores
#pragma unroll
        for (int it = 0; it < 4; ++it) {
            int ci   = it * 256 + tid;
            int cbl  = ci >> 6;        // 0..15 (16-col block within slab)
            int lane = ci & 63;
            int fr = lane & 15, q = lane >> 4;
            uint4 v = *(const uint4*)&P[(cbl * 16 + fr) * 40 + q * 8];
            int ot = ob * 2 + (cbl >> 3);
            int cb = cbl & 7;
            size_t idx = ((((size_t)(e * 8 + ot) * 32 + dz) * 8 + cb) * 64 + lane) * 8;
            *(uint4*)(Wbp + idx) = v;
        }
    }
}

// ---------------------------------------------------------------------------
// Kernel 1b: deterministic stream compaction, SINGLE-PASS (r17, kept).
// Each thread owns 4 consecutive tokens (int4 route load), wave shfl-scan
// + one barrier.  toklist entry = n | (slot<<16).
// ---------------------------------------------------------------------------
__global__ __launch_bounds__(1024) void build_lists(
    const int* __restrict__ route, const float2* __restrict__ gpair,
    int* __restrict__ toklist, float* __restrict__ gatelist,
    int* __restrict__ counts)
{
    int g = blockIdx.x;              // t*8 + e
    int t = g >> 3, e = g & 7;
    int tid = threadIdx.x;
    int wave = tid >> 6, lane = tid & 63;

    __shared__ int waveSum[16];

    int4 r4 = *(const int4*)(route + t * N_ + tid * 4);
    int rr[4] = {r4.x, r4.y, r4.z, r4.w};
    int sel[4], slot[4], mycnt = 0;
#pragma unroll
    for (int j = 0; j < 4; ++j) {
        int e0 = rr[j] & 255, e1 = (rr[j] >> 8) & 255;
        sel[j]  = (e0 == e) || (e1 == e);
        slot[j] = (e0 == e) ? 0 : 1;
        mycnt  += sel[j];
    }
    int x = mycnt;
#pragma unroll
    for (int off = 1; off < 64; off <<= 1) {
        int y = __shfl_up(x, off, 64);
        if (lane >= off) x += y;
    }
    if (lane == 63) waveSum[wave] = x;
    __syncthreads();
    int woff = 0, total = 0;
#pragma unroll
    for (int w = 0; w < 16; ++w) {
        int s = waveSum[w];
        total += s;
        woff += (w < wave) ? s : 0;
    }
    int p = woff + x - mycnt;        // exclusive prefix
#pragma unroll
    for (int j = 0; j < 4; ++j) {
        if (sel[j]) {
            int n = tid * 4 + j;
            toklist[g * N_ + p] = n | (slot[j] << 16);
            float2 gp = gpair[t * N_ + n];
            gatelist[g * N_ + p] = (slot[j] == 0) ? gp.x : gp.y;
            ++p;
        }
    }
    if (tid == 0) counts[g] = total;
}

// ---------------------------------------------------------------------------
// Kernel 3: grouped GEMM = r15 exact (63us, best) + STRAGGLER-FIRST
// dispatch: ~half the groups have cnt>1024, so ~64 mt=8 tiles used to
// dispatch AFTER the 1024-block bulk and run as a low-occupancy tail
// (~15-25us).  Dispatch order now: mt=8 first, then mt=0..7 bulk, then
// phantoms (qm 9..31).
// ---------------------------------------------------------------------------
__global__ __launch_bounds__(512, 4) void moe_gemm(
    const unsigned short* __restrict__ xb,   // [T*N][D] bf16
    const unsigned short* __restrict__ Wbp,  // fragment-order Wf (see prep)
    const int* __restrict__ toklist, const float* __restrict__ gatelist,
    const int* __restrict__ counts, float* __restrict__ out)
{
    int lin = blockIdx.x;            // 0..4095
    int qm  = lin >> 7;
    int mt  = (qm == 0) ? 8 : (qm <= 8 ? qm - 1 : qm);   // stragglers first
    int u   = lin & 127;
    int xcd = u & 7;                 // == lin % 8 == hw XCD round-robin
    int v   = u >> 3;                // 0..15
    int g   = 2 * xcd + (v >> 3);    // xcd owns groups {2x, 2x+1}
    int ot  = v & 7;
    int t   = g >> 3;

    int cnt = counts[g];
    int m0 = mt * BM;
    if (m0 >= cnt) return;

    __shared__ __align__(16) unsigned short As[2][BM * BK];  // 16 KB
    __shared__ int   tokS[BM];
    __shared__ float gateS[BM];

    int tid = threadIdx.x;
    if (tid < BM) {
        int r = m0 + tid;
        tokS[tid]  = (r < cnt) ? toklist[g * N_ + r]  : -1;
        gateS[tid] = (r < cnt) ? gatelist[g * N_ + r] : 0.f;
    }
    __syncthreads();   // queues drained entering the pipeline

    int wave = tid >> 6, lane = tid & 63;   // 8 waves
    // A staging: wave w stages 16-row chunk w (rows 16w..16w+15), 1 KB.
    // lane l -> row (l>>2) of chunk, LDS granule (l&3); source granule
    // sg = (l&3)^((l>>3)&3): LDS pos p of row r holds granule p^((r>>1)&3).
    int lr = lane >> 2;
    int sg = (lane & 3) ^ ((lane >> 3) & 3);
    int ar = wave * 16 + lr;
    int tok = max(tokS[ar], 0) & 0xFFFF;     // junk rows masked in epilogue
    const unsigned short* ag = xb + ((size_t)(t * N_ + tok)) * D_ + sg * 8;

    // B fragment pointers: e8 = (g&7)*8+ot; per-ks stride 4096 shorts;
    // per-cb stride 512; lane offset lane*8.
    const unsigned short* wf =
        Wbp + ((size_t)((g & 7) * 8 + ot) * 32) * 4096;
    int cb0 = (wave >> 1) * 2;
    const unsigned short* bp0 = wf + cb0 * 512 + lane * 8;
    const unsigned short* bp1 = bp0 + 512;

    int fr = lane & 15, q = lane >> 4;
    int wm = (wave & 1) * 64;                // 2 x 4 wave grid: 64 x 32 / wave
    int wn = (wave >> 1) * 32;
    int fp = (q ^ ((fr >> 1) & 3)) * 8;      // read-side swizzled granule

    f32x4 acc[4][2];
#pragma unroll
    for (int mi = 0; mi < 4; ++mi)
#pragma unroll
        for (int ni = 0; ni < 2; ++ni) acc[mi][ni] = (f32x4){0.f, 0.f, 0.f, 0.f};

    short8 bf0[2], bf1[2];

    // prologue: A(0) then (fence) B(0) -- order pins A oldest in the queue
    gld16(ag, &As[0][wave * 512]);
    asm volatile("" ::: "memory");
    bf0[0] = *(const short8*)(bp0);
    bf0[1] = *(const short8*)(bp1);

#define KSTEP(CUR, NXT, BC, BNX, IT)                                           \
    {                                                                          \
        asm volatile("s_waitcnt vmcnt(2)" ::: "memory"); /* A(IT) landed */    \
        __builtin_amdgcn_s_barrier();                                          \
        asm volatile("" ::: "memory");   /* no LDS ops cross the barrier */    \
        int kk = (IT) + 1;                                                     \
        if (kk < D_ / BK) {                                                    \
            gld16(ag + (size_t)kk * BK, &As[NXT][wave * 512]);                 \
            asm volatile("" ::: "memory");  /* pin A-before-B issue order */   \
            BNX[0] = *(const short8*)(bp0 + (size_t)kk * 4096);                \
            BNX[1] = *(const short8*)(bp1 + (size_t)kk * 4096);                \
        }                                                                      \
        short8 af[4];                                                          \
        _Pragma("unroll") for (int mi = 0; mi < 4; ++mi)                       \
            af[mi] = *(const short8*)(&As[CUR][(wm + mi * 16 + fr) * BK + fp]);\
        _Pragma("unroll") for (int mi = 0; mi < 4; ++mi) {                     \
            acc[mi][0] = __builtin_amdgcn_mfma_f32_16x16x32_bf16(              \
                af[mi], BC[0], acc[mi][0], 0, 0, 0);                           \
            acc[mi][1] = __builtin_amdgcn_mfma_f32_16x16x32_bf16(              \
                af[mi], BC[1], acc[mi][1], 0, 0, 0);                           \
        }                                                                      \
    }

    for (int it = 0; it < D_ / BK; it += 2) {
        KSTEP(0, 1, bf0, bf1, it)
        KSTEP(1, 0, bf1, bf0, it + 1)
    }
#undef KSTEP

    // epilogue: C/D layout col = lane&15, row = q*4 + reg  [m89/m91]
    // bf16 slot-pack: slot s -> half s of the fp32 word; combine_kernel sums.
    float* outb = out + (size_t)t * N_ * O_;
    int ncol = ot * 128 + wn + fr;
#pragma unroll
    for (int mi = 0; mi < 4; ++mi) {
#pragma unroll
        for (int r = 0; r < 4; ++r) {
            int ml = wm + mi * 16 + q * 4 + r;
            int ent = tokS[ml];
            if (ent >= 0) {
                int tokk = ent & 0xFFFF;
                int slot = ent >> 16;
                float gate = gateS[ml];
#pragma unroll
                for (int ni = 0; ni < 2; ++ni) {
                    unsigned short* p =
                        (unsigned short*)(outb + (size_t)tokk * O_ + ncol + ni * 16);
                    p[slot] = f2bf(gate * acc[mi][ni][r]);
                }
            }
        }
    }
}

// ---------------------------------------------------------------------------
// Kernel 4: combine the two bf16 slot halves of each out word into fp32.
// ---------------------------------------------------------------------------
__global__ __launch_bounds__(256) void combine_kernel(float* __restrict__ out)
{
    size_t i = ((size_t)blockIdx.x * 256 + threadIdx.x) * 4;
    unsigned* po = (unsigned*)out;
    uint4 v = *(uint4*)(po + i);
    float4 r;
    union { unsigned u; float f; } a, b;
#define CMB(comp, src) a.u = (src) << 16; b.u = (src) & 0xFFFF0000u; comp = a.f + b.f
    CMB(r.x, v.x); CMB(r.y, v.y); CMB(r.z, v.z); CMB(r.w, v.w);
#undef CMB
    *(float4*)(out + i) = r;
}

// ---------------------------------------------------------------------------
extern "C" void kernel_launch(void* const* d_in, const int* in_sizes, int n_in,
                              void* d_out, int out_size, void* d_ws, size_t ws_size,
                              hipStream_t stream)
{
    const float* x  = (const float*)d_in[0];
    const float* Wg = (const float*)d_in[1];
    const float* We = (const float*)d_in[2];
    float* out = (float*)d_out;

    char* ws = (char*)d_ws;
    unsigned short* xb   = (unsigned short*)(ws);               // 16,777,216 B
    unsigned short* Wbp  = (unsigned short*)(ws + 16777216);    // 16,777,216 B
    int*   toklist       = (int*)  (ws + 33554432);             //    262,144 B
    float* gatelist      = (float*)(ws + 33816576);             //    262,144 B
    int*   counts        = (int*)  (ws + 34078720);             //        256 B
    int*   route         = (int*)  (ws + 34078976);             //     32,768 B
    float2* gpair        = (float2*)(ws + 34111744);            //     65,536 B

    prep_kernel<<<1536, 256, 0, stream>>>(x, Wg, We, xb, Wbp, route, gpair);
    build_lists<<<T_ * E_, 1024, 0, stream>>>(route, gpair, toklist, gatelist, counts);
    moe_gemm<<<(N_ / BM) * 8 * (T_ * E_), 512, 0, stream>>>(
        xb, Wbp, toklist, gatelist, counts, out);
    combine_kernel<<<((size_t)T_ * N_ * O_) / (256 * 4), 256, 0, stream>>>(out);
}